// Round 7
// baseline (900.066 us; speedup 1.0000x reference)
//
#include <hip/hip_runtime.h>

typedef unsigned short ushort_t;
typedef __bf16 bf16x8 __attribute__((ext_vector_type(8)));
typedef __bf16 bf16x2 __attribute__((ext_vector_type(2)));
typedef float f32x4 __attribute__((ext_vector_type(4)));
typedef float f32x16 __attribute__((ext_vector_type(16)));

#define LOG2E 1.4426950408889634f
#define LN2   0.6931471805599453f

__device__ __forceinline__ ushort_t f2bf(float f) {
    unsigned u;
    __builtin_memcpy(&u, &f, 4);
    u += 0x7fffu + ((u >> 16) & 1u);   // RNE
    return (ushort_t)(u >> 16);
}

// inputs pre-scaled by log2(e): silu2(y) = y*sigmoid2(y) = log2e*silu(x).
// W1 staged unscaled (log2e cancels vs ln2); b1 scaled by log2e at use;
// LN2 compensation folded once into the final per-row sum.
__device__ __forceinline__ float silu2(float y) {
    float e = __builtin_amdgcn_exp2f(-y);
    return y * __builtin_amdgcn_rcpf(1.0f + e);
}

__device__ __forceinline__ float rdlane(float v, int l) {
    return __builtin_bit_cast(float, __builtin_amdgcn_readlane(__builtin_bit_cast(int, v), l));
}

// ============ 32x32x16 swapped-operand GEMM design (R7) ============
// acc[mt] = W1tile(mt) x H0^T + 0 ; D[m=hidden][n=teacher-row].
// C/D (guide, verified table): col=lane&31 = teacher-row; row=(reg&3)+
// 8*(reg>>2)+4*(lane>>5) + mt*32 = hidden h. Lane owns ONE teacher-row,
// 64 h-values -> layer-2 dot fully in-lane; reduce = 1 shfl_xor(32).
// A-frag (W1): lane holds W1[mt*32+(lane&31)][ks*16+(lane>>5)*8+j].
// B-frag (H0^T): lane holds H0[col=lane&31][k=ks*16+(lane>>5)*8+j].
//
// sH0 swizzle (derived, see bank math): data (h, col) of frag ks=h>>4
// stored at slot sigma = q1h*32 + (col ^ ks ^ (q1h<<1)), q1h=(h>>3)&1,
// ushort addr = ks*512 + sigma*8 + (h&7).
//  - writes (per le, 64 lanes, col const): bank = ((col^ks^(q1h<<1))&7)*4
//    + (lane&3) -> 32 distinct x2 = 2-way (free).
//  - reads (b128, per ks): slot bijective in lane, quarter-wave spans 16
//    contiguous slots -> conflict-free.
//
// R5/R6 LESSON: swapped 16x16 with fused per-mt epilogue spilled (1.9-3.3
// GB scratch FETCH) regardless of nominal live size. This structure keeps
// the R1-proven shape: ks-outer GEMM, all-acc in AGPRs, epilogue strictly
// after, B-frags transient (no afr array live across the GEMM).
// Spill watch: FETCH_SIZE (~27 MB = clean).
//
// LDS: sW1 32 KB + sH0 8 KB/wave * 4 = 64 KB exactly -> 2 blocks/CU.
// b1/W2 epilogue constants come from global (512 B each, L1-resident).
// __launch_bounds__(256,2): VGPR cap 256 under either 2nd-arg reading.

// Packed scatter accumulator: one f64 atomic carries sum + 65536*count.
#define CNT_UNIT 65536.0

__global__ __launch_bounds__(256, 2) void mlp_kernel(
    const float* __restrict__ v,    // [N,3] f32
    const float* __restrict__ rij,  // [E,3] f32
    const float* __restrict__ W0,   // [128,4]
    const float* __restrict__ b0,   // [128]
    const float* __restrict__ W1,   // [128,128] (n,k)
    const float* __restrict__ b1,   // [128]
    const float* __restrict__ W2,   // [128]
    const float* __restrict__ b2,   // [1]
    const int* __restrict__ eidx,   // [2,E] int32
    double* __restrict__ acc_i, double* __restrict__ acc_j,
    int E, int nchunks)             // chunk = 64 edges (4 waves x 16)
{
    __shared__ ushort_t sW1[16384];     // 32 KB: [f=mt*8+ks][lane 64][8]
    __shared__ ushort_t sH0[4][4096];   // 8 KB/wave: [ks 8][slot 64][8], swizzled

    const int tid  = threadIdx.x;
    const int lane = tid & 63;
    const int wave = tid >> 6;

    // ---- stage W1 (f32 -> bf16) into 32x32 A-frag layout ----
#pragma unroll
    for (int s = 0; s < 8; s++) {
        int fl = s * 256 + tid;          // 0..2047 frag-lane slots
        int f  = fl >> 6, L = fl & 63;
        int mt = f >> 3, ks = f & 7;
        const float* src = W1 + (mt * 32 + (L & 31)) * 128 + ks * 16 + (L >> 5) * 8;
        ushort_t tmp[8];
#pragma unroll
        for (int t = 0; t < 8; t++) tmp[t] = f2bf(src[t]);
        *(uint4*)(&sW1[fl * 8]) = *(const uint4*)tmp;
    }

    // ---- per-lane layer-0 constants (log2e folded); lane covers h=2l,2l+1 ----
    float4 w0q[2]; float b0v[2];
#pragma unroll
    for (int kk = 0; kk < 2; kk++) {
        int h = 2 * lane + kk;
        w0q[kk].x = W0[h * 4 + 0] * LOG2E;
        w0q[kk].y = W0[h * 4 + 1] * LOG2E;
        w0q[kk].z = W0[h * 4 + 2] * LOG2E;
        w0q[kk].w = W0[h * 4 + 3] * LOG2E;
        b0v[kk]   = b0[h] * LOG2E;
    }
    const float b2f = b2[0];

    __syncthreads();   // sW1 ready; hot loop below is barrier-free

    const int q1  = lane >> 5;          // 0/1: k-half (reader) / h-half owner
    const int c31 = lane & 31;
    // writer constants (for this lane's h-pair {2l, 2l+1}):
    const int ksw = lane >> 3;          // frag of h-pair
    const int q1h = (lane >> 2) & 1;    // (h>>3)&1
    const int KX  = ksw ^ (q1h << 1);
    const int wbase_w = ksw * 256 + q1h * 128 + (lane & 3);  // u32 units
    // reader constant:
    const int rx = c31 ^ (q1 << 1);

    const int ple  = lane >> 2;     // edge-in-wave this lane preloads
    const int comp = lane & 3;      // 0..2: v component, 3: |r|/H

    // ---- gather preload for one chunk (lane-parallel) ----
    auto preload = [&](int ch, float& val_o, int& idx_o) {
        float val = 0.f; int idxr = 0;
        int pe = ch * 64 + wave * 16 + ple;
        if (ch < nchunks && pe < E) {
            if (comp == 3) {
                float r0 = rij[3 * pe], r1 = rij[3 * pe + 1], r2 = rij[3 * pe + 2];
                val = sqrtf(fmaf(r0, r0, fmaf(r1, r1, r2 * r2))) * (1.0f / 3.0f);
            } else {
                int i = eidx[pe], jj = eidx[E + pe];
                idxr = (comp == 1) ? jj : i;
                val = v[3 * i + comp] - v[3 * jj + comp];
            }
        }
        val_o = val; idx_o = idxr;
    };

    float val; int idxr;
    preload(blockIdx.x, val, idxr);   // prologue load for first chunk

    for (int chunk = blockIdx.x; chunk < nchunks; chunk += gridDim.x) {
        const float val_cur = val;
        const int   idx_cur = idxr;
        // issue next chunk's gathers now; consumed one full iteration later
        preload(chunk + (int)gridDim.x, val, idxr);

        const int ebase = chunk * 64 + wave * 16;
        unsigned* H0w = (unsigned*)sH0[wave];

        // ===== phase A: layer0 for 16 edges -> swizzled H0^T frags =====
#pragma unroll
        for (int le = 0; le < 16; le++) {
            float vx = rdlane(val_cur, le * 4 + 0);
            float vy = rdlane(val_cur, le * 4 + 1);
            float vz = rdlane(val_cur, le * 4 + 2);
            float rr = rdlane(val_cur, le * 4 + 3);
            float cc0 = fmaf(w0q[0].x, rr, b0v[0]);
            float dd0 = fmaf(w0q[0].y, vx, fmaf(w0q[0].z, vy, w0q[0].w * vz));
            float cc1 = fmaf(w0q[1].x, rr, b0v[1]);
            float dd1 = fmaf(w0q[1].y, vx, fmaf(w0q[1].z, vy, w0q[1].w * vz));
            float s0 = silu2(cc0 + dd0);   // row i, h=2l
            float s1 = silu2(cc0 - dd0);   // row j, h=2l
            float s2 = silu2(cc1 + dd1);   // row i, h=2l+1
            float s3 = silu2(cc1 - dd1);   // row j, h=2l+1
            bf16x2 pki, pkj;
            pki[0] = (__bf16)s0; pki[1] = (__bf16)s2;   // (h, h+1) for col=2le
            pkj[0] = (__bf16)s1; pkj[1] = (__bf16)s3;   // (h, h+1) for col=2le+1
            int c0 = (2 * le) ^ KX;        // swizzled slot low-bits, col=2le
            int cj = c0 ^ 1;               // col=2le+1
            H0w[wbase_w + c0 * 4] = __builtin_bit_cast(unsigned, pki);
            H0w[wbase_w + cj * 4] = __builtin_bit_cast(unsigned, pkj);
        }

        // ===== GEMM: acc[mt] = W1tile(mt) x H0^T, ks-outer, acc in AGPRs =====
        f32x16 acc[4];
#pragma unroll
        for (int mt = 0; mt < 4; mt++)
#pragma unroll
            for (int r = 0; r < 16; r++) acc[mt][r] = 0.0f;

#pragma unroll
        for (int ks = 0; ks < 8; ks++) {
            bf16x8 h0f = *(const bf16x8*)(&sH0[wave][ks * 512 + q1 * 256 + (rx ^ ks) * 8]);
#pragma unroll
            for (int mt = 0; mt < 4; mt++) {
                bf16x8 bb = *(const bf16x8*)(&sW1[((mt * 8 + ks) * 64 + lane) * 8]);
                acc[mt] = __builtin_amdgcn_mfma_f32_32x32x16_bf16(bb, h0f, acc[mt], 0, 0, 0);
            }
        }

        // ===== epilogue: rs = sum_h silu2(acc + b1') * W2  (all in-lane) =====
        // reg r of tile mt: h = mt*32 + (r&3) + 8*(r>>2) + 4*q1.
        float rsA = 0.f, rsB = 0.f;
#pragma unroll
        for (int mt = 0; mt < 4; mt++) {
            const float* bp = b1 + mt * 32 + 4 * q1;
            const float* wp = W2 + mt * 32 + 4 * q1;
#pragma unroll
            for (int g = 0; g < 4; g++) {
                f32x4 bq = *(const f32x4*)(bp + 8 * g);
                f32x4 wq = *(const f32x4*)(wp + 8 * g);
#pragma unroll
                for (int r2 = 0; r2 < 4; r2++) {
                    float y = fmaf(bq[r2], LOG2E, acc[mt][g * 4 + r2]);
                    float t = silu2(y) * wq[r2];
                    if (g & 1) rsB += t; else rsA += t;
                }
            }
        }
        float s = rsA + rsB;
        s += __shfl_xor(s, 32, 64);        // combine q1 halves of h
        int el   = c31 >> 1;               // edge within wave's 16
        int node = __shfl(idx_cur, 4 * el + (c31 & 1), 64);
        int e    = ebase + el;
        if (q1 == 0 && e < E) {
            double contrib = (double)fmaf(s, LN2, b2f) + CNT_UNIT;
            double* dst = (c31 & 1) ? acc_j : acc_i;   // odd teacher-row = x_j
            atomicAdd(&dst[node], contrib);
        }
        // wave-local LDS WAR across chunks is safe: one wave's DS ops are in-order.
    }
}

__global__ void finalize_kernel(const double* __restrict__ acc_i,
                                const double* __restrict__ acc_j,
                                float* __restrict__ out, int N)
{
    int n = blockIdx.x * 256 + threadIdx.x;
    if (n < N) {
        double ti = acc_i[n], tj = acc_j[n];
        double ci = rint(ti * (1.0 / CNT_UNIT));
        double cj = rint(tj * (1.0 / CNT_UNIT));
        double si = ti - ci * CNT_UNIT;
        double sj = tj - cj * CNT_UNIT;
        out[n] = (float)(si / fmax(ci, 1.0) + sj / fmax(cj, 1.0));
    }
}

extern "C" void kernel_launch(void* const* d_in, const int* in_sizes, int n_in,
                              void* d_out, int out_size, void* d_ws, size_t ws_size,
                              hipStream_t stream) {
    const float* v   = (const float*)d_in[0];
    const float* rij = (const float*)d_in[1];
    const float* W0  = (const float*)d_in[2];
    const float* b0  = (const float*)d_in[3];
    const float* W1  = (const float*)d_in[4];
    const float* b1  = (const float*)d_in[5];
    const float* W2  = (const float*)d_in[6];
    const float* b2  = (const float*)d_in[7];
    const int* eidx  = (const int*)d_in[8];

    const int E = in_sizes[1] / 3;
    const int N = out_size;

    double* acc_i = (double*)d_ws;
    double* acc_j = acc_i + N;

    hipMemsetAsync(d_ws, 0, (size_t)2 * N * sizeof(double), stream);

    int nchunks = (E + 63) / 64;
    int grid = nchunks < 512 ? nchunks : 512;   // 2 blocks/CU resident
    mlp_kernel<<<grid, 256, 0, stream>>>(v, rij, W0, b0, W1, b1, W2, b2, eidx,
                                         acc_i, acc_j, E, nchunks);
    finalize_kernel<<<(N + 255) / 256, 256, 0, stream>>>(acc_i, acc_j,
                                                         (float*)d_out, N);
}

// Round 8
// 376.354 us; speedup vs baseline: 2.3915x; 2.3915x over previous
//
#include <hip/hip_runtime.h>

typedef unsigned short ushort_t;
typedef __bf16 bf16x8 __attribute__((ext_vector_type(8)));
typedef __bf16 bf16x2 __attribute__((ext_vector_type(2)));
typedef float f32x4 __attribute__((ext_vector_type(4)));

#define LOG2E 1.4426950408889634f
#define LN2   0.6931471805599453f

__device__ __forceinline__ ushort_t f2bf(float f) {
    unsigned u;
    __builtin_memcpy(&u, &f, 4);
    u += 0x7fffu + ((u >> 16) & 1u);   // RNE
    return (ushort_t)(u >> 16);
}

// inputs pre-scaled by log2(e): silu2(y) = y * sigmoid2(y) = log2e*silu(x).
// Downstream weights carry the compensating ln2. Simple form (one rcp per
// silu): R4 proved the quad-batched rcp variant net-regresses.
__device__ __forceinline__ float silu2(float y) {
    float e = __builtin_amdgcn_exp2f(-y);
    return y * __builtin_amdgcn_rcpf(1.0f + e);
}

// XOR-swizzled A-fragment LDS layout for 16x16x32 bf16 MFMA (verified):
// element (row,k) -> frag  = (k>>5)   [within a wave's 16-row region]
//                    slot  = ((row&15) ^ ((k>>5)&3) ^ (((k>>3)&3)<<2))
//                            + 16*((k>>3)&3)                             [16 B]
//                    byte  = (k&7)*2
// Reads: b128, 64 distinct slots, conflict-free. Writes: 2-way (free).
//
// STRUCTURE LOCKED TO THE R1 SHAPE (proven spill-free at VGPR=84):
// ks-outer GEMM, A=H0 frags cached in regs, B=W1 frag read+consumed,
// acc[2][8] used ONLY as MFMA C-chain, epilogue strictly after the GEMM.
// R5/R6/R7 all tried swapped-operand / fused-epilogue / 32x32 variants;
// ALL spilled (1.7-3.9 GB scratch FETCH, 26:1 read:write = loop state
// reloaded every chunk) regardless of nominal live-set size. DO NOT
// revisit that family on this toolchain.
//
// R8 change (this round): phase A's 64 v_readlane broadcasts replaced by
// lane-parallel preload ds_write into sX + 16 broadcast ds_read_b128
// (same-address reads are bank-conflict-free). Moves ~64 ops/chunk-wave
// off the saturated VALU port (64% busy) onto the DS pipe and removes
// readlane SGPR dep-chains. sX double-buffered by chunk parity; each wave
// touches only its own slice -> still barrier-free (wave DS in-order).
//
// LDS: sW1 32 KB + sH0 16 KB + sX 2 KB = 50 KB -> 3 blocks/CU (12 waves).
// __launch_bounds__(256,3): 2nd arg behaves as min BLOCKS/CU here (R3:
// (512,4) -> 64-VGPR cap -> spill disaster). Cap ~170 VGPR. DO NOT RAISE.

// Packed scatter accumulator: one f64 atomic carries sum + 65536*count.
#define CNT_UNIT 65536.0

__global__ __launch_bounds__(256, 3) void mlp_kernel(
    const float* __restrict__ v,    // [N,3] f32
    const float* __restrict__ rij,  // [E,3] f32
    const float* __restrict__ W0,   // [128,4]
    const float* __restrict__ b0,   // [128]
    const float* __restrict__ W1,   // [128,128] (n,k)
    const float* __restrict__ b1,   // [128]
    const float* __restrict__ W2,   // [128]
    const float* __restrict__ b2,   // [1]
    const int* __restrict__ eidx,   // [2,E] int32
    double* __restrict__ acc_i, double* __restrict__ acc_j,
    int E, int nchunks)             // chunk = 64 edges (4 waves x 16)
{
    __shared__ ushort_t sW1[16384];    // 32 KB, frag layout (unswizzled)
    __shared__ ushort_t sH0[8192];     // 16 KB, XOR-swizzled; wave w owns frags [4w,4w+4)
    __shared__ float    sX[2][4][16][4]; // 2 KB: [parity][wave][edge][vx,vy,vz,rr]

    const int tid  = threadIdx.x;
    const int lane = tid & 63;
    const int wave = tid >> 6;

    // ---- stage W1 (f32 -> bf16) into LDS (once per block) ----
    // W1's silu-prescale (log2e) cancels against h0' (ln2): staged UNSCALED.
    {
        int n = tid >> 1, half = tid & 1;
        const float* src = W1 + n * 128;
#pragma unroll
        for (int dk = 0; dk < 8; dk++) {
            int k0   = half * 64 + dk * 8;
            int frag = (n >> 4) * 4 + (k0 >> 5);
            int slot = (n & 15) + 16 * ((k0 >> 3) & 3);
            ushort_t tmp[8];
#pragma unroll
            for (int t = 0; t < 8; t++) tmp[t] = f2bf(src[k0 + t]);
            *(uint4*)(&sW1[frag * 512 + slot * 8]) = *(const uint4*)tmp;
        }
    }

    // ---- per-lane constants (log2e folded) ----
    float4 w0q[2]; float b0v[2];
#pragma unroll
    for (int kk = 0; kk < 2; kk++) {
        int h = 2 * lane + kk;
        w0q[kk].x = W0[h * 4 + 0] * LOG2E;
        w0q[kk].y = W0[h * 4 + 1] * LOG2E;
        w0q[kk].z = W0[h * 4 + 2] * LOG2E;
        w0q[kk].w = W0[h * 4 + 3] * LOG2E;
        b0v[kk]   = b0[h] * LOG2E;
    }
    float b1v[8], w2v[8];
#pragma unroll
    for (int nt = 0; nt < 8; nt++) {
        int ccol = nt * 16 + (lane & 15);
        b1v[nt] = b1[ccol] * LOG2E;   // pre-activation scale for layer-1 silu2
        w2v[nt] = W2[ccol] * LN2;     // compensates log2e in silu2 output
    }
    const float b2f = b2[0];

    __syncthreads();   // sW1 ready; hot loop below is barrier-free

    const int q = lane >> 4, c = lane & 15, p = (lane >> 2) & 3, bsub = lane & 3;
    const int ple  = lane >> 2;     // edge-in-wave this lane preloads
    const int comp = lane & 3;      // 0..2: v component, 3: |r|/H

    // ---- gather preload: lane-parallel, lands in sX[wpar] (wave slice) ----
    auto preload = [&](int ch, int wpar, int& idx_o) {
        float val = 0.f; int idxr = 0;
        int pe = ch * 64 + wave * 16 + ple;
        if (ch < nchunks && pe < E) {
            if (comp == 3) {
                float r0 = rij[3 * pe], r1 = rij[3 * pe + 1], r2 = rij[3 * pe + 2];
                val = sqrtf(fmaf(r0, r0, fmaf(r1, r1, r2 * r2))) * (1.0f / 3.0f);
            } else {
                int i = eidx[pe], jj = eidx[E + pe];
                idxr = (comp == 1) ? jj : i;
                val = v[3 * i + comp] - v[3 * jj + comp];
            }
        }
        sX[wpar][wave][ple][comp] = val;   // wave-local slice, in-order DS
        idx_o = idxr;
    };

    int idxr;
    int par = 0;
    preload(blockIdx.x, 0, idxr);   // prologue load for first chunk -> buf 0

    for (int chunk = blockIdx.x; chunk < nchunks; chunk += gridDim.x) {
        const int idx_cur = idxr;
        // issue next chunk's gathers into the other parity buffer
        preload(chunk + (int)gridDim.x, par ^ 1, idxr);

        const int ebase = chunk * 64 + wave * 16;
        const float* xbase = &sX[par][wave][0][0];

        // ===== two temporal halves: layer0 -> 16-row LDS region -> H0 frags =====
        bf16x8 afr[2][4];
#pragma unroll
        for (int half = 0; half < 2; ++half) {
#pragma unroll
            for (int le = 0; le < 8; le++) {
                int se = half * 8 + le;
                f32x4 xv = *(const f32x4*)(xbase + se * 4);  // broadcast read
                float vx = xv[0], vy = xv[1], vz = xv[2], rr = xv[3];
                float cc0 = fmaf(w0q[0].x, rr, b0v[0]);
                float dd0 = fmaf(w0q[0].y, vx, fmaf(w0q[0].z, vy, w0q[0].w * vz));
                float cc1 = fmaf(w0q[1].x, rr, b0v[1]);
                float dd1 = fmaf(w0q[1].y, vx, fmaf(w0q[1].z, vy, w0q[1].w * vz));
                float s0 = silu2(cc0 + dd0);   // x_i, h=2l
                float s1 = silu2(cc0 - dd0);   // x_j, h=2l
                float s2 = silu2(cc1 + dd1);   // x_i, h=2l+1
                float s3 = silu2(cc1 - dd1);   // x_j, h=2l+1
                bf16x2 pki, pkj;
                pki[0] = (__bf16)s0; pki[1] = (__bf16)s2;
                pkj[0] = (__bf16)s1; pkj[1] = (__bf16)s3;
                int mi = 2 * le;                  // x_i row in [0,16); x_j row = mi+1
                int fr = wave * 4 + q;
                int sli = ((mi ^ q ^ (p << 2)) & 15) + (p << 4);
                int slj = (((mi + 1) ^ q ^ (p << 2)) & 15) + (p << 4);
                ((unsigned*)sH0)[fr * 256 + sli * 4 + bsub] = __builtin_bit_cast(unsigned, pki);
                ((unsigned*)sH0)[fr * 256 + slj * 4 + bsub] = __builtin_bit_cast(unsigned, pkj);
            }
            // cache this half's H0 fragments before half 1 overwrites the region
#pragma unroll
            for (int ks = 0; ks < 4; ks++) {
                int sl_rd = (((lane & 15) ^ ks ^ (q << 2)) & 15) + 16 * q;
                afr[half][ks] = *(const bf16x8*)(&sH0[(wave * 4 + ks) * 512 + sl_rd * 8]);
            }
        }

        // ===== GEMM: h1_pre' = H0' @ W1^T + b1' (R1-proven shape) =====
        f32x4 acc[2][8];
#pragma unroll
        for (int t = 0; t < 2; t++)
#pragma unroll
            for (int nt = 0; nt < 8; nt++)
                acc[t][nt] = (f32x4){b1v[nt], b1v[nt], b1v[nt], b1v[nt]};

#pragma unroll
        for (int ks = 0; ks < 4; ks++) {
#pragma unroll
            for (int nt = 0; nt < 8; nt++) {
                bf16x8 bb = *(const bf16x8*)(&sW1[(nt * 4 + ks) * 512 + lane * 8]);
                acc[0][nt] = __builtin_amdgcn_mfma_f32_16x16x32_bf16(afr[0][ks], bb, acc[0][nt], 0, 0, 0);
                acc[1][nt] = __builtin_amdgcn_mfma_f32_16x16x32_bf16(afr[1][ks], bb, acc[1][nt], 0, 0, 0);
            }
        }

        // ===== epilogue: silu2(h1') . (W2*ln2) -> +b2 -> packed f64 scatter-add =====
        float rs[2][4] = {{0.f, 0.f, 0.f, 0.f}, {0.f, 0.f, 0.f, 0.f}};
#pragma unroll
        for (int t = 0; t < 2; t++)
#pragma unroll
            for (int nt = 0; nt < 8; nt++)
#pragma unroll
                for (int r = 0; r < 4; r++) {
                    float x = acc[t][nt][r];          // b1' folded into acc init
                    rs[t][r] = fmaf(silu2(x), w2v[nt], rs[t][r]);
                }
#pragma unroll
        for (int t = 0; t < 2; t++)
#pragma unroll
            for (int r = 0; r < 4; r++) {
                float s = rs[t][r];
                s += __shfl_xor(s, 1, 64);
                s += __shfl_xor(s, 2, 64);
                s += __shfl_xor(s, 4, 64);
                s += __shfl_xor(s, 8, 64);
                int el  = t * 8 + q * 2 + (r >> 1);        // edge within wave's 16
                int src = el * 4 + (r & 1);                // comp0 lane holds i, comp1 holds j
                int node = __shfl(idx_cur, src, 64);
                int e = ebase + el;
                if (c == 0 && e < E) {
                    double contrib = (double)(s + b2f) + CNT_UNIT;
                    if (r & 1) atomicAdd(&acc_j[node], contrib);
                    else       atomicAdd(&acc_i[node], contrib);
                }
            }
        par ^= 1;
        // wave-local LDS WAR across chunks is safe: one wave's DS ops are in-order.
    }
}

__global__ void finalize_kernel(const double* __restrict__ acc_i,
                                const double* __restrict__ acc_j,
                                float* __restrict__ out, int N)
{
    int n = blockIdx.x * 256 + threadIdx.x;
    if (n < N) {
        double ti = acc_i[n], tj = acc_j[n];
        double ci = rint(ti * (1.0 / CNT_UNIT));
        double cj = rint(tj * (1.0 / CNT_UNIT));
        double si = ti - ci * CNT_UNIT;
        double sj = tj - cj * CNT_UNIT;
        out[n] = (float)(si / fmax(ci, 1.0) + sj / fmax(cj, 1.0));
    }
}

extern "C" void kernel_launch(void* const* d_in, const int* in_sizes, int n_in,
                              void* d_out, int out_size, void* d_ws, size_t ws_size,
                              hipStream_t stream) {
    const float* v   = (const float*)d_in[0];
    const float* rij = (const float*)d_in[1];
    const float* W0  = (const float*)d_in[2];
    const float* b0  = (const float*)d_in[3];
    const float* W1  = (const float*)d_in[4];
    const float* b1  = (const float*)d_in[5];
    const float* W2  = (const float*)d_in[6];
    const float* b2  = (const float*)d_in[7];
    const int* eidx  = (const int*)d_in[8];

    const int E = in_sizes[1] / 3;
    const int N = out_size;

    double* acc_i = (double*)d_ws;
    double* acc_j = acc_i + N;

    hipMemsetAsync(d_ws, 0, (size_t)2 * N * sizeof(double), stream);

    int nchunks = (E + 63) / 64;
    int grid = nchunks < 768 ? nchunks : 768;
    mlp_kernel<<<grid, 256, 0, stream>>>(v, rij, W0, b0, W1, b1, W2, b2, eidx,
                                         acc_i, acc_j, E, nchunks);
    finalize_kernel<<<(N + 255) / 256, 256, 0, stream>>>(acc_i, acc_j,
                                                         (float*)d_out, N);
}